// Round 1
// baseline (1793.757 us; speedup 1.0000x reference)
//
#include <hip/hip_runtime.h>

#define H 184
#define MDH 16
#define L1D 188

// ---------------- zero init (agg, deg, xmax, h0) ----------------
__global__ void zero_kernel(float* __restrict__ p, int n) {
    int i = blockIdx.x * blockDim.x + threadIdx.x;
    if (i < n) p[i] = 0.0f;
}

// ---------------- edge scatter: agg += x[src]*w, deg += 1 ----------------
__global__ __launch_bounds__(256) void edge_kernel(
        const float* __restrict__ nf,       // (N,6)
        const int*   __restrict__ ei,       // (2,E)
        const float* __restrict__ ew,       // (E,)
        float* __restrict__ agg,            // (N,4)
        float* __restrict__ deg,            // (N,)
        int E) {
    int e = blockIdx.x * blockDim.x + threadIdx.x;
    if (e >= E) return;
    int src = ei[e];
    int dst = ei[E + e];
    float w = ew[e];
    const float* xr = nf + (size_t)src * 6;
    float m0 = xr[0] * w;
    float m1 = xr[1] * w;
    float m2 = xr[2] * w;
    float m3 = xr[3] * w;
    float* a = agg + (size_t)dst * 4;
    atomicAdd(a + 0, m0);
    atomicAdd(a + 1, m1);
    atomicAdd(a + 2, m2);
    atomicAdd(a + 3, m3);
    atomicAdd(deg + dst, 1.0f);
}

// ---------------- per-node dense layer + global feature max ----------------
// thread j (< 184) owns feature j; block walks a contiguous node range.
__global__ __launch_bounds__(192) void node_kernel(
        const float* __restrict__ nf,
        const float* __restrict__ agg,
        const float* __restrict__ deg,
        const float* __restrict__ W_rel,    // (4,184)
        const float* __restrict__ b_rel,    // (184,)
        const float* __restrict__ W_root,   // (4,184)
        const int*   __restrict__ centerp,
        unsigned int* __restrict__ xmax_bits, // (184,) float bits, init 0
        float* __restrict__ h0,               // (184,)
        int N, int nodes_per_block) {
    int j = threadIdx.x;
    if (j >= H) return;
    int center = *centerp;
    int n0 = blockIdx.x * nodes_per_block;
    int n1 = n0 + nodes_per_block;
    if (n1 > N) n1 = N;

    float wr0 = W_rel[0 * H + j], wr1 = W_rel[1 * H + j];
    float wr2 = W_rel[2 * H + j], wr3 = W_rel[3 * H + j];
    float wo0 = W_root[0 * H + j], wo1 = W_root[1 * H + j];
    float wo2 = W_root[2 * H + j], wo3 = W_root[3 * H + j];
    float b = b_rel[j];

    float mx = 0.0f;
    for (int n = n0; n < n1; ++n) {
        float4 a = ((const float4*)agg)[n];          // agg row, 16B aligned
        float d = deg[n];
        float inv = 1.0f / fmaxf(d, 1.0f);
        const float* xr = nf + (size_t)n * 6;
        float x0 = xr[0], x1 = xr[1], x2 = xr[2], x3 = xr[3];
        float v = b
                + (a.x * inv) * wr0 + (a.y * inv) * wr1
                + (a.z * inv) * wr2 + (a.w * inv) * wr3
                + x0 * wo0 + x1 * wo1 + x2 * wo2 + x3 * wo3;
        v = fmaxf(v, 0.0f);
        mx = fmaxf(mx, v);
        if (n == center) h0[j] = v;
    }
    // relu outputs are >= 0, so float bit pattern order == value order
    atomicMax(xmax_bits + j, __float_as_uint(mx));
}

// ---------------- tiny head MLP, one block ----------------
__global__ __launch_bounds__(256) void final_kernel(
        const float* __restrict__ nf,
        const int*   __restrict__ centerp,
        const unsigned int* __restrict__ xmax_bits,
        const float* __restrict__ h0,
        const float* __restrict__ W2,  const float* __restrict__ b2,
        const float* __restrict__ W21, const float* __restrict__ b21,
        const float* __restrict__ W1,  const float* __restrict__ b1,
        const float* __restrict__ W4,  const float* __restrict__ b4,
        float* __restrict__ out) {
    __shared__ float gin[H + MDH];   // 200
    __shared__ float md0[MDH];
    __shared__ float g1[L1D];
    int t = threadIdx.x;
    int center = *centerp;

    if (t < H) gin[t] = h0[t] - __uint_as_float(xmax_bits[t]);
    if (t < MDH) {
        float m0 = nf[(size_t)center * 6 + 4];
        float m1 = nf[(size_t)center * 6 + 5];
        md0[t] = fmaxf(m0 * W2[t] + m1 * W2[MDH + t] + b2[t], 0.0f);
    }
    __syncthreads();
    if (t < MDH) {
        float s = b21[t];
        for (int k = 0; k < MDH; ++k) s += md0[k] * W21[k * MDH + t];
        gin[H + t] = fmaxf(s, 0.0f);
    }
    __syncthreads();
    if (t < L1D) {
        float s = b1[t];
        for (int k = 0; k < H + MDH; ++k) s += gin[k] * W1[k * L1D + t];
        g1[t] = fmaxf(s, 0.0f);
    }
    __syncthreads();
    if (t < 5) {
        float s = b4[t];
        for (int k = 0; k < L1D; ++k) s += g1[k] * W4[k * 5 + t];
        out[t] = s;
    }
}

extern "C" void kernel_launch(void* const* d_in, const int* in_sizes, int n_in,
                              void* d_out, int out_size, void* d_ws, size_t ws_size,
                              hipStream_t stream) {
    const float* nf      = (const float*)d_in[0];   // (N,6)
    const int*   ei      = (const int*)  d_in[1];   // (2,E)
    const float* ew      = (const float*)d_in[2];   // (E,)
    const int*   centerp = (const int*)  d_in[3];   // scalar
    const float* W_rel   = (const float*)d_in[4];
    const float* b_rel   = (const float*)d_in[5];
    const float* W_root  = (const float*)d_in[6];
    const float* W2      = (const float*)d_in[7];
    const float* b2      = (const float*)d_in[8];
    const float* W21     = (const float*)d_in[9];
    const float* b21     = (const float*)d_in[10];
    const float* W1      = (const float*)d_in[11];
    const float* b1      = (const float*)d_in[12];
    const float* W4      = (const float*)d_in[13];
    const float* b4      = (const float*)d_in[14];
    float* out = (float*)d_out;

    const int N = in_sizes[0] / 6;
    const int E = in_sizes[1] / 2;

    // workspace layout (floats)
    float* agg = (float*)d_ws;                 // N*4
    float* deg = agg + (size_t)N * 4;          // N
    unsigned int* xmax_bits = (unsigned int*)(deg + N); // 184
    float* h0 = (float*)(xmax_bits + H);       // 184

    const int zero_n = N * 5 + 2 * H;
    zero_kernel<<<(zero_n + 255) / 256, 256, 0, stream>>>((float*)d_ws, zero_n);

    edge_kernel<<<(E + 255) / 256, 256, 0, stream>>>(nf, ei, ew, agg, deg, E);

    const int blocks = 512;
    const int npb = (N + blocks - 1) / blocks;
    node_kernel<<<blocks, 192, 0, stream>>>(nf, agg, deg, W_rel, b_rel, W_root,
                                            centerp, xmax_bits, h0, N, npb);

    final_kernel<<<1, 256, 0, stream>>>(nf, centerp, xmax_bits, h0,
                                        W2, b2, W21, b21, W1, b1, W4, b4, out);
}

// Round 2
// 821.146 us; speedup vs baseline: 2.1845x; 2.1845x over previous
//
#include <hip/hip_runtime.h>

#define H 184
#define MDH 16
#define L1D 188
#define CHUNK 256

// ---------------- zero init ----------------
__global__ void zero_kernel(int* __restrict__ p, int n) {
    int i = blockIdx.x * blockDim.x + threadIdx.x;
    if (i < n) p[i] = 0;
}

// ---------------- pass 1: histogram + per-edge rank ----------------
__global__ __launch_bounds__(256) void hist_rank_kernel(
        const int* __restrict__ ei, int* __restrict__ cnt,
        int* __restrict__ rank, int E) {
    int e = blockIdx.x * blockDim.x + threadIdx.x;
    if (e >= E) return;
    int dst = ei[E + e];
    rank[e] = atomicAdd(cnt + dst, 1);
}

// ---------------- scan stage A: per-chunk sums ----------------
__global__ __launch_bounds__(CHUNK) void chunk_sum_kernel(
        const int* __restrict__ cnt, int* __restrict__ csum, int N) {
    __shared__ int s[CHUNK];
    int i = blockIdx.x * CHUNK + threadIdx.x;
    s[threadIdx.x] = (i < N) ? cnt[i] : 0;
    __syncthreads();
    for (int st = CHUNK / 2; st > 0; st >>= 1) {
        if (threadIdx.x < st) s[threadIdx.x] += s[threadIdx.x + st];
        __syncthreads();
    }
    if (threadIdx.x == 0) csum[blockIdx.x] = s[0];
}

// ---------------- scan stage B: exclusive scan of chunk sums (<=1024) ----------------
__global__ __launch_bounds__(1024) void top_scan_kernel(int* __restrict__ csum, int nchunks) {
    __shared__ int s[1024];
    int t = threadIdx.x;
    int v = (t < nchunks) ? csum[t] : 0;
    s[t] = v;
    __syncthreads();
    for (int st = 1; st < 1024; st <<= 1) {
        int u = (t >= st) ? s[t - st] : 0;
        __syncthreads();
        s[t] += u;
        __syncthreads();
    }
    if (t < nchunks) csum[t] = s[t] - v;   // exclusive
}

// ---------------- scan stage C: per-element exclusive offsets ----------------
__global__ __launch_bounds__(CHUNK) void chunk_scan_kernel(
        const int* __restrict__ cnt, const int* __restrict__ csum,
        int* __restrict__ off, int N) {
    __shared__ int s[CHUNK];
    int c = blockIdx.x;
    int i = c * CHUNK + threadIdx.x;
    int v = (i < N) ? cnt[i] : 0;
    s[threadIdx.x] = v;
    __syncthreads();
    for (int st = 1; st < CHUNK; st <<= 1) {
        int u = (threadIdx.x >= st) ? s[threadIdx.x - st] : 0;
        __syncthreads();
        s[threadIdx.x] += u;
        __syncthreads();
    }
    if (i < N) off[i] = csum[c] + s[threadIdx.x] - v;  // exclusive
}

// ---------------- pass 2: scatter (src,w) into sorted position — no atomics ----------------
__global__ __launch_bounds__(256) void scatter_kernel(
        const int* __restrict__ ei, const float* __restrict__ ew,
        const int* __restrict__ rank, const int* __restrict__ off,
        int2* __restrict__ sorted, int E) {
    int e = blockIdx.x * blockDim.x + threadIdx.x;
    if (e >= E) return;
    int dst = ei[E + e];
    int src = ei[e];
    float w = ew[e];
    int pos = off[dst] + rank[e];
    sorted[pos] = make_int2(src, __float_as_int(w));
}

// ---------------- pass 3: per-node gather-reduce — no atomics ----------------
__global__ __launch_bounds__(256) void gather_kernel(
        const float* __restrict__ nf, const int2* __restrict__ sorted,
        const int* __restrict__ off, const int* __restrict__ cnt,
        float* __restrict__ agg, int N) {
    int n = blockIdx.x * blockDim.x + threadIdx.x;
    if (n >= N) return;
    int o = off[n], c = cnt[n];
    float a0 = 0.f, a1 = 0.f, a2 = 0.f, a3 = 0.f;
    for (int k = 0; k < c; ++k) {
        int2 sw = sorted[o + k];
        const float* xr = nf + (size_t)sw.x * 6;
        float w = __int_as_float(sw.y);
        a0 += xr[0] * w; a1 += xr[1] * w; a2 += xr[2] * w; a3 += xr[3] * w;
    }
    ((float4*)agg)[n] = make_float4(a0, a1, a2, a3);
}

// ---------------- fallback: atomic scatter (used only if ws too small) ----------------
__global__ __launch_bounds__(256) void edge_atomic_kernel(
        const float* __restrict__ nf, const int* __restrict__ ei,
        const float* __restrict__ ew, float* __restrict__ agg,
        int* __restrict__ cnt, int E) {
    int e = blockIdx.x * blockDim.x + threadIdx.x;
    if (e >= E) return;
    int src = ei[e];
    int dst = ei[E + e];
    float w = ew[e];
    const float* xr = nf + (size_t)src * 6;
    float* a = agg + (size_t)dst * 4;
    atomicAdd(a + 0, xr[0] * w);
    atomicAdd(a + 1, xr[1] * w);
    atomicAdd(a + 2, xr[2] * w);
    atomicAdd(a + 3, xr[3] * w);
    atomicAdd(cnt + dst, 1);
}

// ---------------- per-node dense layer + global feature max ----------------
__global__ __launch_bounds__(192) void node_kernel(
        const float* __restrict__ nf,
        const float* __restrict__ agg,
        const int*   __restrict__ cnt,       // degree as int
        const float* __restrict__ W_rel, const float* __restrict__ b_rel,
        const float* __restrict__ W_root,
        const int*   __restrict__ centerp,
        unsigned int* __restrict__ xmax_bits,
        float* __restrict__ h0,
        int N, int nodes_per_block) {
    int j = threadIdx.x;
    if (j >= H) return;
    int center = *centerp;
    int n0 = blockIdx.x * nodes_per_block;
    int n1 = n0 + nodes_per_block;
    if (n1 > N) n1 = N;

    float wr0 = W_rel[0 * H + j], wr1 = W_rel[1 * H + j];
    float wr2 = W_rel[2 * H + j], wr3 = W_rel[3 * H + j];
    float wo0 = W_root[0 * H + j], wo1 = W_root[1 * H + j];
    float wo2 = W_root[2 * H + j], wo3 = W_root[3 * H + j];
    float b = b_rel[j];

    float mx = 0.0f;
    for (int n = n0; n < n1; ++n) {
        float4 a = ((const float4*)agg)[n];
        float inv = 1.0f / fmaxf((float)cnt[n], 1.0f);
        const float* xr = nf + (size_t)n * 6;
        float v = b
                + (a.x * inv) * wr0 + (a.y * inv) * wr1
                + (a.z * inv) * wr2 + (a.w * inv) * wr3
                + xr[0] * wo0 + xr[1] * wo1 + xr[2] * wo2 + xr[3] * wo3;
        v = fmaxf(v, 0.0f);
        mx = fmaxf(mx, v);
        if (n == center) h0[j] = v;
    }
    atomicMax(xmax_bits + j, __float_as_uint(mx));  // relu out >= 0
}

// ---------------- tiny head MLP, one block ----------------
__global__ __launch_bounds__(256) void final_kernel(
        const float* __restrict__ nf,
        const int*   __restrict__ centerp,
        const unsigned int* __restrict__ xmax_bits,
        const float* __restrict__ h0,
        const float* __restrict__ W2,  const float* __restrict__ b2,
        const float* __restrict__ W21, const float* __restrict__ b21,
        const float* __restrict__ W1,  const float* __restrict__ b1,
        const float* __restrict__ W4,  const float* __restrict__ b4,
        float* __restrict__ out) {
    __shared__ float gin[H + MDH];
    __shared__ float md0[MDH];
    __shared__ float g1[L1D];
    int t = threadIdx.x;
    int center = *centerp;

    if (t < H) gin[t] = h0[t] - __uint_as_float(xmax_bits[t]);
    if (t < MDH) {
        float m0 = nf[(size_t)center * 6 + 4];
        float m1 = nf[(size_t)center * 6 + 5];
        md0[t] = fmaxf(m0 * W2[t] + m1 * W2[MDH + t] + b2[t], 0.0f);
    }
    __syncthreads();
    if (t < MDH) {
        float s = b21[t];
        for (int k = 0; k < MDH; ++k) s += md0[k] * W21[k * MDH + t];
        gin[H + t] = fmaxf(s, 0.0f);
    }
    __syncthreads();
    if (t < L1D) {
        float s = b1[t];
        for (int k = 0; k < H + MDH; ++k) s += gin[k] * W1[k * L1D + t];
        g1[t] = fmaxf(s, 0.0f);
    }
    __syncthreads();
    if (t < 5) {
        float s = b4[t];
        for (int k = 0; k < L1D; ++k) s += g1[k] * W4[k * 5 + t];
        out[t] = s;
    }
}

extern "C" void kernel_launch(void* const* d_in, const int* in_sizes, int n_in,
                              void* d_out, int out_size, void* d_ws, size_t ws_size,
                              hipStream_t stream) {
    const float* nf      = (const float*)d_in[0];
    const int*   ei      = (const int*)  d_in[1];
    const float* ew      = (const float*)d_in[2];
    const int*   centerp = (const int*)  d_in[3];
    const float* W_rel   = (const float*)d_in[4];
    const float* b_rel   = (const float*)d_in[5];
    const float* W_root  = (const float*)d_in[6];
    const float* W2      = (const float*)d_in[7];
    const float* b2      = (const float*)d_in[8];
    const float* W21     = (const float*)d_in[9];
    const float* b21     = (const float*)d_in[10];
    const float* W1      = (const float*)d_in[11];
    const float* b1      = (const float*)d_in[12];
    const float* W4      = (const float*)d_in[13];
    const float* b4      = (const float*)d_in[14];
    float* out = (float*)d_out;

    const int N = in_sizes[0] / 6;
    const int E = in_sizes[1] / 2;
    const int nchunks = (N + CHUNK - 1) / CHUNK;   // 782 for N=200000, must be <=1024

    // workspace layout
    float*        agg  = (float*)d_ws;                       // N*4 f32
    int*          cnt  = (int*)(agg + (size_t)N * 4);        // N
    unsigned int* xmax = (unsigned int*)(cnt + N);           // H
    float*        h0   = (float*)(xmax + H);                 // H
    int*          off  = (int*)(h0 + H);                     // N
    int*          csum = off + N;                            // 1024
    int*          rank = csum + 1024;                        // E
    int2*         sorted = (int2*)(rank + E);                // E * 8B

    size_t need = (size_t)((char*)(sorted + E) - (char*)d_ws);
    bool sort_path = (ws_size >= need) && (nchunks <= 1024);

    if (sort_path) {
        // zero: cnt + xmax (contiguous)
        zero_kernel<<<(N + H + 255) / 256, 256, 0, stream>>>(cnt, N + H);
        hist_rank_kernel<<<(E + 255) / 256, 256, 0, stream>>>(ei, cnt, rank, E);
        chunk_sum_kernel<<<nchunks, CHUNK, 0, stream>>>(cnt, csum, N);
        top_scan_kernel<<<1, 1024, 0, stream>>>(csum, nchunks);
        chunk_scan_kernel<<<nchunks, CHUNK, 0, stream>>>(cnt, csum, off, N);
        scatter_kernel<<<(E + 255) / 256, 256, 0, stream>>>(ei, ew, rank, off, sorted, E);
        gather_kernel<<<(N + 255) / 256, 256, 0, stream>>>(nf, sorted, off, cnt, agg, N);
    } else {
        // fallback: zero agg + cnt + xmax (contiguous), atomic scatter
        zero_kernel<<<(N * 5 + H + 255) / 256, 256, 0, stream>>>((int*)agg, N * 5 + H);
        edge_atomic_kernel<<<(E + 255) / 256, 256, 0, stream>>>(nf, ei, ew, agg, cnt, E);
    }

    const int blocks = 1024;
    const int npb = (N + blocks - 1) / blocks;
    node_kernel<<<blocks, 192, 0, stream>>>(nf, agg, cnt, W_rel, b_rel, W_root,
                                            centerp, xmax, h0, N, npb);
    final_kernel<<<1, 256, 0, stream>>>(nf, centerp, xmax, h0,
                                        W2, b2, W21, b21, W1, b1, W4, b4, out);
}